// Round 14
// baseline (157.475 us; speedup 1.0000x reference)
//
#include <hip/hip_runtime.h>
#include <hip/hip_bf16.h>
#include <stdint.h>

// B=4, M=256, N=64, D=512, C=1024
// out[b,m,n,c] = log_softmax_c( tanh(pe[b,m,:] + pd[b,n,:]) . W2[c,:] + b2[c] )
// pe = enc @ W1[:, :D]^T ; pd = dec @ W1[:, D:]^T + b1
// log_softmax WITHOUT the max pass (logits bounded ~18 -> f32-safe).
// GEMM: v_mfma_f32_32x32x16_bf16 (half the instructions of 16x16x32).
// W2 re-tiled in prep; SINGLE layout definition used by BOTH sides:
//   idx = w*32768 + ks*1024 + cb*512 + l*8 + e      (elements, 2^19 total)
//   col = w*64 + cb*32 + (l&31),  k = ks*16 + (l>>5)*8 + e
// -> every B-fragment load is 64 lanes x 16B contiguous = 1KB coalesced.

typedef __bf16         bf16x8 __attribute__((ext_vector_type(8)));
typedef float          f32x4  __attribute__((ext_vector_type(4)));
typedef float          f32x16 __attribute__((ext_vector_type(16)));
typedef unsigned short u16x8  __attribute__((ext_vector_type(8)));

__device__ __forceinline__ unsigned short f2bf(float f) {
  unsigned int u = __float_as_uint(f);
  u += 0x7fffu + ((u >> 16) & 1u);          // RNE
  return (unsigned short)(u >> 16);
}

__device__ __forceinline__ f32x4 mfma16(u16x8 a, u16x8 b, f32x4 c) {
  return __builtin_amdgcn_mfma_f32_16x16x32_bf16(
      __builtin_bit_cast(bf16x8, a), __builtin_bit_cast(bf16x8, b), c, 0, 0, 0);
}
__device__ __forceinline__ f32x16 mfma32(u16x8 a, u16x8 b, f32x16 c) {
  return __builtin_amdgcn_mfma_f32_32x32x16_bf16(
      __builtin_bit_cast(bf16x8, a), __builtin_bit_cast(bf16x8, b), c, 0, 0, 0);
}

// ---------------- prep: f32 -> bf16 conversions + W2 tiling (32x32 order) ----
__global__ __launch_bounds__(256) void prep_kernel(
    const float* __restrict__ enc, const float* __restrict__ dec,
    const float* __restrict__ W1,  const float* __restrict__ W2,
    unsigned short* __restrict__ encB, unsigned short* __restrict__ decB,
    unsigned short* __restrict__ W1eB, unsigned short* __restrict__ W1dB,
    unsigned short* __restrict__ W2t)
{
  const int i = blockIdx.x * 256 + threadIdx.x;   // 0 .. 524287 (2^19)
  encB[i] = f2bf(enc[i]);
  {
    // decode idx = w*32768 + ks*1024 + cb*512 + l*8 + e
    const int e  = i & 7;
    const int l  = (i >> 3) & 63;
    const int cb = (i >> 9) & 1;
    const int ks = (i >> 10) & 31;
    const int w  = i >> 15;                        // 0..15
    const int col = w * 64 + cb * 32 + (l & 31);
    const int k   = ks * 16 + (l >> 5) * 8 + e;
    W2t[i] = f2bf(W2[col * 512 + k]);
  }
  if (i < 262144) {                                // W1 is [512][1024]
    const int k = i >> 9, d = i & 511;
    W1eB[i] = f2bf(W1[k * 1024 + d]);
    W1dB[i] = f2bf(W1[k * 1024 + 512 + d]);
  }
  if (i < 131072) decB[i] = f2bf(dec[i]);
}

// ---------------- proj: out[r][c] = sum_d A[r][d]*Wt[c][d] (+bias[c]) ----------------
__global__ __launch_bounds__(256) void proj_kernel(
    const unsigned short* __restrict__ A, const unsigned short* __restrict__ Wt,
    const float* __restrict__ bias, float* __restrict__ out)
{
  const int rtile = blockIdx.x >> 3;
  const int ctile = blockIdx.x & 7;
  const int w = threadIdx.x >> 6;
  const int l = threadIdx.x & 63;
  const int q = l >> 4, ln = l & 15;

  f32x4 acc[4] = {};
  const unsigned short* Ab = A  + (size_t)(rtile * 64 + ln) * 512 + q * 8;
  const unsigned short* Wb = Wt + (size_t)(ctile * 64 + w * 16 + ln) * 512 + q * 8;

#pragma unroll 4
  for (int ks = 0; ks < 16; ++ks) {
    u16x8 bv = *(const u16x8*)(Wb + ks * 32);
#pragma unroll
    for (int rf = 0; rf < 4; ++rf) {
      u16x8 av = *(const u16x8*)(Ab + rf * 16 * 512 + ks * 32);
      acc[rf] = mfma16(av, bv, acc[rf]);
    }
  }
  const int col = ctile * 64 + w * 16 + ln;
  const float bv = bias ? bias[col] : 0.0f;
#pragma unroll
  for (int rf = 0; rf < 4; ++rf)
#pragma unroll
    for (int j = 0; j < 4; ++j)
      out[(size_t)(rtile * 64 + rf * 16 + q * 4 + j) * 512 + col] = acc[rf][j] + bv;
}

// ---------------- joint: fused tanh-GEMM(32x32) + bias + log_softmax ----------------
// grid = B*M = 1024 blocks, block = 1024 threads (16 waves).
// Wave w: all 64 rows x cols [w*64, w*64+64) via 2x2 fragments of 32x32.
// acc = 2x2 f32x16 = 64 f32/thread.
__global__ __launch_bounds__(1024) void joint_kernel(
    const float* __restrict__ pe, const float* __restrict__ pd,
    const unsigned short* __restrict__ W2t, const float* __restrict__ b2,
    float* __restrict__ out)
{
  __shared__ unsigned short A_sh[64 * 512];   // 64 KiB, XOR-swizzled bf16 tile
  __shared__ float red[64][17];               // per-row, per-wave sum2exp (padded)
  __shared__ float lse_sh[64];

  const int blk = blockIdx.x;            // b*256 + m
  const int b   = blk >> 8;
  const int tid = threadIdx.x;
  const int w = tid >> 6, l = tid & 63;
  const int lo = l & 31, hi = l >> 5;

  // ---- generate A[n][d] = tanh(pe[m,d] + pd[n,d]) into swizzled LDS ----
  // wave w owns rows w*4..w*4+3; lane l owns d = l*8..l*8+7 (coalesced).
  // phys 16B-slot = logical_slot ^ (row & 7)   (R12-verified form).
  {
    const float* per = pe + (size_t)blk * 512 + l * 8;
    const float4 pe0 = *(const float4*)(per);
    const float4 pe1 = *(const float4*)(per + 4);
#pragma unroll
    for (int r = 0; r < 4; ++r) {
      const int n = (w << 2) | r;
      const float* pdr = pd + (size_t)((b << 6) | n) * 512 + l * 8;
      const float4 q0 = *(const float4*)(pdr);
      const float4 q1 = *(const float4*)(pdr + 4);
      float x[8] = {pe0.x + q0.x, pe0.y + q0.y, pe0.z + q0.z, pe0.w + q0.w,
                    pe1.x + q1.x, pe1.y + q1.y, pe1.z + q1.z, pe1.w + q1.w};
      u16x8 pk;
#pragma unroll
      for (int e = 0; e < 8; ++e) {
        const float ex = __expf(2.0f * x[e]);                    // tanh = 1 - 2/(e^2x+1)
        const float tv = 1.0f - 2.0f * __builtin_amdgcn_rcpf(ex + 1.0f);
        pk[e] = f2bf(tv);
      }
      *(u16x8*)((char*)A_sh + n * 1024 + ((l ^ (n & 7)) << 4)) = pk;
    }
  }
  __syncthreads();

  // ---- GEMM: wave w owns cols [w*64, w*64+64), rows 0..63 (2x2 frags) ----
  f32x16 acc[2][2];
#pragma unroll
  for (int rb = 0; rb < 2; ++rb)
#pragma unroll
    for (int cb = 0; cb < 2; ++cb) acc[rb][cb] = (f32x16)(0.f);

  // A: lane reads row rb*32+lo, logical 16B-slot 2*ks+hi, phys = slot ^ (lo&7).
  const char* Abase = (const char*)A_sh + lo * 1024;           // + rb*32768
  const int x7 = lo & 7;
  // B: wave-region stream, lane offset l*16B; + ks*1024el + cb*512el.
  const unsigned short* Wb = W2t + (size_t)w * 32768 + l * 8;

  for (int ks = 0; ks < 32; ++ks) {
    u16x8 bv[2], av[2];
#pragma unroll
    for (int cb = 0; cb < 2; ++cb)
      bv[cb] = *(const u16x8*)(Wb + ks * 1024 + cb * 512);
#pragma unroll
    for (int rb = 0; rb < 2; ++rb)
      av[rb] = *(const u16x8*)(Abase + rb * 32768 + (((2 * ks + hi) ^ x7) << 4));
#pragma unroll
    for (int rb = 0; rb < 2; ++rb)
#pragma unroll
      for (int cb = 0; cb < 2; ++cb)
        acc[rb][cb] = mfma32(av[rb], bv[cb], acc[rb][cb]);
  }

  // ---- epilogue: + b2, row-sums of 2^(x*log2e), per-rb to limit live regs ----
  // thread holds: cols {w*64 + cb*32 + lo}, rows {rb*32 + (reg&3)+8*(reg>>2)+4*hi}.
  const float L2E = 1.4426950408889634f;
  const float LN2 = 0.6931471805599453f;
  float b2v[2];
#pragma unroll
  for (int cb = 0; cb < 2; ++cb) b2v[cb] = b2[w * 64 + cb * 32 + lo];

#pragma unroll
  for (int rb = 0; rb < 2; ++rb) {
    float s[16];
#pragma unroll
    for (int reg = 0; reg < 16; ++reg) {
      const float x0 = acc[rb][0][reg] + b2v[0];
      const float x1 = acc[rb][1][reg] + b2v[1];
      acc[rb][0][reg] = x0;
      acc[rb][1][reg] = x1;
      s[reg] = __builtin_amdgcn_exp2f(x0 * L2E) + __builtin_amdgcn_exp2f(x1 * L2E);
    }
#pragma unroll
    for (int o = 1; o < 32; o <<= 1)
#pragma unroll
      for (int reg = 0; reg < 16; ++reg)
        s[reg] += __shfl_xor(s[reg], o);
    if (lo == 0) {
#pragma unroll
      for (int reg = 0; reg < 16; ++reg) {
        const int row = rb * 32 + (reg & 3) + 8 * (reg >> 2) + 4 * hi;
        red[row][w] = s[reg];
      }
    }
  }
  __syncthreads();

  // merge the 16 wave-partials: thread tid<64 handles row tid
  if (tid < 64) {
    float s = red[tid][0];
#pragma unroll
    for (int ww = 1; ww < 16; ++ww) s += red[tid][ww];
    lse_sh[tid] = LN2 * __builtin_amdgcn_logf(s);   // v_log_f32 = log2
  }
  __syncthreads();

  // final: out = acc - lse
  float* outb = out + (size_t)blk * 65536 + w * 64 + lo;
#pragma unroll
  for (int rb = 0; rb < 2; ++rb)
#pragma unroll
    for (int reg = 0; reg < 16; ++reg) {
      const int row = rb * 32 + (reg & 3) + 8 * (reg >> 2) + 4 * hi;
      const float lse = lse_sh[row];
      float* orow = outb + (size_t)row * 1024;
      orow[0]  = acc[rb][0][reg] - lse;
      orow[32] = acc[rb][1][reg] - lse;
    }
}

extern "C" void kernel_launch(void* const* d_in, const int* in_sizes, int n_in,
                              void* d_out, int out_size, void* d_ws, size_t ws_size,
                              hipStream_t stream) {
  (void)in_sizes; (void)n_in; (void)out_size; (void)ws_size;
  const float* enc = (const float*)d_in[0];
  const float* dec = (const float*)d_in[1];
  const float* W1  = (const float*)d_in[2];
  const float* b1  = (const float*)d_in[3];
  const float* W2  = (const float*)d_in[4];
  const float* b2  = (const float*)d_in[5];
  float* out = (float*)d_out;

  char* ws = (char*)d_ws;
  unsigned short* encB = (unsigned short*)(ws + 0);        // 1 MiB   (524288 el)
  unsigned short* decB = (unsigned short*)(ws + 1048576);  // 256 KiB (131072 el)
  unsigned short* W1eB = (unsigned short*)(ws + 1310720);  // 512 KiB (262144 el)
  unsigned short* W1dB = (unsigned short*)(ws + 1835008);  // 512 KiB (262144 el)
  unsigned short* W2t  = (unsigned short*)(ws + 2359296);  // 1 MiB   (524288 el, tiled)
  float*          pe   = (float*)(ws + 3407872);           // 2 MiB  [1024][512]
  float*          pd   = (float*)(ws + 5505024);           // 512 KiB [256][512]

  prep_kernel<<<2048, 256, 0, stream>>>(enc, dec, W1, W2, encB, decB, W1eB, W1dB, W2t);
  proj_kernel<<<128, 256, 0, stream>>>(encB, W1eB, nullptr, pe);   // pe: 1024x512
  proj_kernel<<< 32, 256, 0, stream>>>(decB, W1dB, b1,      pd);   // pd:  256x512
  joint_kernel<<<1024, 1024, 0, stream>>>(pe, pd, W2t, b2, out);
}

// Round 16
// 152.037 us; speedup vs baseline: 1.0358x; 1.0358x over previous
//
#include <hip/hip_runtime.h>
#include <hip/hip_bf16.h>
#include <stdint.h>

// B=4, M=256, N=64, D=512, C=1024
// out[b,m,n,c] = log_softmax_c( tanh(pe[b,m,:] + pd[b,n,:]) . W2[c,:] + b2[c] )
// pe = enc @ W1[:, :D]^T ; pd = dec @ W1[:, D:]^T + b1
// log_softmax WITHOUT the max pass (logits bounded ~18 -> f32-safe).
// GEMM: v_mfma_f32_32x32x16_bf16; B staged via global_load_lds into per-wave
// double-buffered LDS panels (no barriers in the k-loop; counted vmcnt(2)).
// RACE GUARDS vs R15: (1) b2 loads consumed before the barrier via asm
// keep-alive so NO non-stage vmem is outstanding in the loop (the vmcnt
// count relies on this); (2) sched_barrier(0) pins stage/wait ordering.
// W2t layout (both sides): idx = w*32768 + ks*1024 + cb*512 + l*8 + e
//   col = w*64 + cb*32 + (l&31),  k = ks*16 + (l>>5)*8 + e

typedef __bf16         bf16x8 __attribute__((ext_vector_type(8)));
typedef float          f32x4  __attribute__((ext_vector_type(4)));
typedef float          f32x16 __attribute__((ext_vector_type(16)));
typedef unsigned short u16x8  __attribute__((ext_vector_type(8)));

__device__ __forceinline__ unsigned short f2bf(float f) {
  unsigned int u = __float_as_uint(f);
  u += 0x7fffu + ((u >> 16) & 1u);          // RNE
  return (unsigned short)(u >> 16);
}

__device__ __forceinline__ f32x4 mfma16(u16x8 a, u16x8 b, f32x4 c) {
  return __builtin_amdgcn_mfma_f32_16x16x32_bf16(
      __builtin_bit_cast(bf16x8, a), __builtin_bit_cast(bf16x8, b), c, 0, 0, 0);
}
__device__ __forceinline__ f32x16 mfma32(u16x8 a, u16x8 b, f32x16 c) {
  return __builtin_amdgcn_mfma_f32_32x32x16_bf16(
      __builtin_bit_cast(bf16x8, a), __builtin_bit_cast(bf16x8, b), c, 0, 0, 0);
}

// async global->LDS, 16B/lane: lane i's 16B lands at ldsbase + i*16.
__device__ __forceinline__ void stage16(const void* g, void* l) {
  __builtin_amdgcn_global_load_lds(
      (const __attribute__((address_space(1))) void*)g,
      (__attribute__((address_space(3))) void*)l, 16, 0, 0);
}

// ---------------- prep: f32 -> bf16 conversions + W2 tiling (32x32 order) ----
__global__ __launch_bounds__(256) void prep_kernel(
    const float* __restrict__ enc, const float* __restrict__ dec,
    const float* __restrict__ W1,  const float* __restrict__ W2,
    unsigned short* __restrict__ encB, unsigned short* __restrict__ decB,
    unsigned short* __restrict__ W1eB, unsigned short* __restrict__ W1dB,
    unsigned short* __restrict__ W2t)
{
  const int i = blockIdx.x * 256 + threadIdx.x;   // 0 .. 524287 (2^19)
  encB[i] = f2bf(enc[i]);
  {
    // decode idx = w*32768 + ks*1024 + cb*512 + l*8 + e
    const int e  = i & 7;
    const int l  = (i >> 3) & 63;
    const int cb = (i >> 9) & 1;
    const int ks = (i >> 10) & 31;
    const int w  = i >> 15;                        // 0..15
    const int col = w * 64 + cb * 32 + (l & 31);
    const int k   = ks * 16 + (l >> 5) * 8 + e;
    W2t[i] = f2bf(W2[col * 512 + k]);
  }
  if (i < 262144) {                                // W1 is [512][1024]
    const int k = i >> 9, d = i & 511;
    W1eB[i] = f2bf(W1[k * 1024 + d]);
    W1dB[i] = f2bf(W1[k * 1024 + 512 + d]);
  }
  if (i < 131072) decB[i] = f2bf(dec[i]);
}

// ---------------- proj (merged): pe = encB@W1e^T ; pd = decB@W1d^T + b1 ------
__global__ __launch_bounds__(256) void proj_kernel(
    const unsigned short* __restrict__ encB, const unsigned short* __restrict__ decB,
    const unsigned short* __restrict__ W1eB, const unsigned short* __restrict__ W1dB,
    const float* __restrict__ b1, float* __restrict__ pe, float* __restrict__ pd)
{
  int bid = blockIdx.x;
  const unsigned short *A, *Wt;
  const float* bias;
  float* out;
  if (bid < 128) { A = encB; Wt = W1eB; bias = nullptr; out = pe; }
  else           { bid -= 128; A = decB; Wt = W1dB; bias = b1; out = pd; }
  const int rtile = bid >> 3;
  const int ctile = bid & 7;
  const int w = threadIdx.x >> 6;
  const int l = threadIdx.x & 63;
  const int q = l >> 4, ln = l & 15;

  f32x4 acc[4] = {};
  const unsigned short* Ab = A  + (size_t)(rtile * 64 + ln) * 512 + q * 8;
  const unsigned short* Wb = Wt + (size_t)(ctile * 64 + w * 16 + ln) * 512 + q * 8;

#pragma unroll 4
  for (int ks = 0; ks < 16; ++ks) {
    u16x8 bv = *(const u16x8*)(Wb + ks * 32);
#pragma unroll
    for (int rf = 0; rf < 4; ++rf) {
      u16x8 av = *(const u16x8*)(Ab + rf * 16 * 512 + ks * 32);
      acc[rf] = mfma16(av, bv, acc[rf]);
    }
  }
  const int col = ctile * 64 + w * 16 + ln;
  const float bv = bias ? bias[col] : 0.0f;
#pragma unroll
  for (int rf = 0; rf < 4; ++rf)
#pragma unroll
    for (int j = 0; j < 4; ++j)
      out[(size_t)(rtile * 64 + rf * 16 + q * 4 + j) * 512 + col] = acc[rf][j] + bv;
}

// ---------------- joint: fused tanh-GEMM(32x32, LDS-staged B) + log_softmax --
// grid = B*M = 1024 blocks, block = 1024 threads (16 waves).
// Wave w: all 64 rows x cols [w*64, w*64+64) via 2x2 fragments of 32x32.
__global__ __launch_bounds__(1024) void joint_kernel(
    const float* __restrict__ pe, const float* __restrict__ pd,
    const unsigned short* __restrict__ W2t, const float* __restrict__ b2,
    float* __restrict__ out)
{
  __shared__ unsigned short A_sh[64 * 512];    // 64 KiB, XOR-swizzled bf16 tile
  __shared__ unsigned short B_sh[16 * 2048];   // 64 KiB: per-wave 2-buf x 1024 els
  __shared__ float red[64][17];                // per-row, per-wave sum2exp (padded)
  __shared__ float lse_sh[64];

  const int blk = blockIdx.x;            // b*256 + m
  const int b   = blk >> 8;
  const int tid = threadIdx.x;
  const int w = tid >> 6, l = tid & 63;
  const int lo = l & 31, hi = l >> 5;

  const unsigned short* Wsrc = W2t + (size_t)w * 32768;   // this wave's panel
  unsigned short* Bdst = B_sh + w * 2048;                 // wave-uniform base

  // stage chunk 0 (buf 0) — L2 latency hides under the gen phase
  stage16(Wsrc + l * 8,       Bdst);
  stage16(Wsrc + 512 + l * 8, Bdst + 512);

  // b2: load AND pin consumption before the barrier (keep-alive) so no
  // non-stage vmem op can be sunk into the k-loop (vmcnt count depends on it)
  float b2v[2];
#pragma unroll
  for (int cb = 0; cb < 2; ++cb) b2v[cb] = b2[w * 64 + cb * 32 + lo];
  asm volatile("" :: "v"(b2v[0]), "v"(b2v[1]));

  // ---- generate A[n][d] = tanh(pe[m,d] + pd[n,d]) into swizzled LDS ----
  // wave w owns rows w*4..w*4+3; lane l owns d = l*8..l*8+7 (coalesced).
  {
    const float* per = pe + (size_t)blk * 512 + l * 8;
    const float4 pe0 = *(const float4*)(per);
    const float4 pe1 = *(const float4*)(per + 4);
#pragma unroll
    for (int r = 0; r < 4; ++r) {
      const int n = (w << 2) | r;
      const float* pdr = pd + (size_t)((b << 6) | n) * 512 + l * 8;
      const float4 q0 = *(const float4*)(pdr);
      const float4 q1 = *(const float4*)(pdr + 4);
      float x[8] = {pe0.x + q0.x, pe0.y + q0.y, pe0.z + q0.z, pe0.w + q0.w,
                    pe1.x + q1.x, pe1.y + q1.y, pe1.z + q1.z, pe1.w + q1.w};
      u16x8 pk;
#pragma unroll
      for (int e = 0; e < 8; ++e) {
        const float ex = __expf(2.0f * x[e]);                    // tanh = 1 - 2/(e^2x+1)
        const float tv = 1.0f - 2.0f * __builtin_amdgcn_rcpf(ex + 1.0f);
        pk[e] = f2bf(tv);
      }
      *(u16x8*)((char*)A_sh + n * 1024 + ((l ^ (n & 7)) << 4)) = pk;
    }
  }
  __syncthreads();   // A ready; drains gen loads + b2 + stage(0): vmcnt = 0 here

  // ---- GEMM: barrier-free k-loop; per-wave private B double-buffer ----
  f32x16 acc[2][2];
#pragma unroll
  for (int rb = 0; rb < 2; ++rb)
#pragma unroll
    for (int cb = 0; cb < 2; ++cb) acc[rb][cb] = (f32x16)(0.f);

  const char* Abase = (const char*)A_sh + lo * 1024;   // + rb*32768
  const int x7 = lo & 7;
  const unsigned short* Bread = B_sh + w * 2048 + l * 8;

#pragma unroll
  for (int ks = 0; ks < 32; ++ks) {
    __builtin_amdgcn_sched_barrier(0);
    if (ks < 31) {
      // stage next chunk into the other buffer (private region, no race)
      stage16(Wsrc + (ks + 1) * 1024 + l * 8,       Bdst + ((ks + 1) & 1) * 1024);
      stage16(Wsrc + (ks + 1) * 1024 + 512 + l * 8, Bdst + ((ks + 1) & 1) * 1024 + 512);
      __builtin_amdgcn_sched_barrier(0);
      asm volatile("s_waitcnt vmcnt(2)" ::: "memory");   // chunk ks landed
    } else {
      asm volatile("s_waitcnt vmcnt(0)" ::: "memory");
    }
    __builtin_amdgcn_sched_barrier(0);

    u16x8 bv[2], av[2];
#pragma unroll
    for (int cb = 0; cb < 2; ++cb)
      bv[cb] = *(const u16x8*)(Bread + (ks & 1) * 1024 + cb * 512);
#pragma unroll
    for (int rb = 0; rb < 2; ++rb)
      av[rb] = *(const u16x8*)(Abase + rb * 32768 + (((2 * ks + hi) ^ x7) << 4));
#pragma unroll
    for (int rb = 0; rb < 2; ++rb)
#pragma unroll
      for (int cb = 0; cb < 2; ++cb)
        acc[rb][cb] = mfma32(av[rb], bv[cb], acc[rb][cb]);
  }

  // ---- epilogue: + b2, row-sums of 2^(x*log2e), per-rb to limit live regs ----
  // thread holds: cols {w*64 + cb*32 + lo}, rows {rb*32 + (reg&3)+8*(reg>>2)+4*hi}.
  const float L2E = 1.4426950408889634f;
  const float LN2 = 0.6931471805599453f;

#pragma unroll
  for (int rb = 0; rb < 2; ++rb) {
    float s[16];
#pragma unroll
    for (int reg = 0; reg < 16; ++reg) {
      const float x0 = acc[rb][0][reg] + b2v[0];
      const float x1 = acc[rb][1][reg] + b2v[1];
      acc[rb][0][reg] = x0;
      acc[rb][1][reg] = x1;
      s[reg] = __builtin_amdgcn_exp2f(x0 * L2E) + __builtin_amdgcn_exp2f(x1 * L2E);
    }
#pragma unroll
    for (int o = 1; o < 32; o <<= 1)
#pragma unroll
      for (int reg = 0; reg < 16; ++reg)
        s[reg] += __shfl_xor(s[reg], o);
    if (lo == 0) {
#pragma unroll
      for (int reg = 0; reg < 16; ++reg) {
        const int row = rb * 32 + (reg & 3) + 8 * (reg >> 2) + 4 * hi;
        red[row][w] = s[reg];
      }
    }
  }
  __syncthreads();

  // merge the 16 wave-partials: thread tid<64 handles row tid
  if (tid < 64) {
    float s = red[tid][0];
#pragma unroll
    for (int ww = 1; ww < 16; ++ww) s += red[tid][ww];
    lse_sh[tid] = LN2 * __builtin_amdgcn_logf(s);   // v_log_f32 = log2
  }
  __syncthreads();

  // final: out = acc - lse
  float* outb = out + (size_t)blk * 65536 + w * 64 + lo;
#pragma unroll
  for (int rb = 0; rb < 2; ++rb)
#pragma unroll
    for (int reg = 0; reg < 16; ++reg) {
      const int row = rb * 32 + (reg & 3) + 8 * (reg >> 2) + 4 * hi;
      const float lse = lse_sh[row];
      float* orow = outb + (size_t)row * 1024;
      orow[0]  = acc[rb][0][reg] - lse;
      orow[32] = acc[rb][1][reg] - lse;
    }
}

extern "C" void kernel_launch(void* const* d_in, const int* in_sizes, int n_in,
                              void* d_out, int out_size, void* d_ws, size_t ws_size,
                              hipStream_t stream) {
  (void)in_sizes; (void)n_in; (void)out_size; (void)ws_size;
  const float* enc = (const float*)d_in[0];
  const float* dec = (const float*)d_in[1];
  const float* W1  = (const float*)d_in[2];
  const float* b1  = (const float*)d_in[3];
  const float* W2  = (const float*)d_in[4];
  const float* b2  = (const float*)d_in[5];
  float* out = (float*)d_out;

  char* ws = (char*)d_ws;
  unsigned short* encB = (unsigned short*)(ws + 0);        // 1 MiB   (524288 el)
  unsigned short* decB = (unsigned short*)(ws + 1048576);  // 256 KiB (131072 el)
  unsigned short* W1eB = (unsigned short*)(ws + 1310720);  // 512 KiB (262144 el)
  unsigned short* W1dB = (unsigned short*)(ws + 1835008);  // 512 KiB (262144 el)
  unsigned short* W2t  = (unsigned short*)(ws + 2359296);  // 1 MiB   (524288 el, tiled)
  float*          pe   = (float*)(ws + 3407872);           // 2 MiB  [1024][512]
  float*          pd   = (float*)(ws + 5505024);           // 512 KiB [256][512]

  prep_kernel<<<2048, 256, 0, stream>>>(enc, dec, W1, W2, encB, decB, W1eB, W1dB, W2t);
  proj_kernel<<<160, 256, 0, stream>>>(encB, decB, W1eB, W1dB, b1, pe, pd);
  joint_kernel<<<1024, 1024, 0, stream>>>(pe, pd, W2t, b2, out);
}